// Round 1
// 290.685 us; speedup vs baseline: 1.2940x; 1.2940x over previous
//
#include <hip/hip_runtime.h>
#include <hip/hip_bf16.h>
#include <hip/hip_fp16.h>
#include <math.h>

#define NEG_SLOPE 0.2f

typedef __attribute__((ext_vector_type(8))) short short8v;
typedef __attribute__((ext_vector_type(4))) float f32x4;

__device__ __forceinline__ float uas(unsigned int u) { return __uint_as_float(u); }

__device__ __forceinline__ unsigned short f2bf(float x) {
    __hip_bfloat16 b = __float2bfloat16(x);
    return *(unsigned short*)&b;
}

// ---------------- W prep: extended bf16 fragment image -----------------------
// Extended B matrix W'[144,256]: rows 0..127 = W; rows 128..135 = head-masked
// attn projections vl[4],vr[4]; rows 136..143 = 0.  Fragment layout (9 ntiles):
//   slot(kstep,ntile) = kstep*9+ntile; lane L=(kg&3)*16+(n&15) holds 8 shorts
//   B'[n][k=kstep*32+(L>>4)*8+j]  -> lane-contiguous 16 B.
__global__ void k_prep(const float* __restrict__ W, const float* __restrict__ al,
                       const float* __restrict__ ar, short* __restrict__ wfrag) {
    int p = blockIdx.x * 256 + threadIdx.x;   // n*32+kg, 0..4607
    if (p >= 144 * 32) return;
    int n = p >> 5, kg = p & 31;
    float v[8];
    if (n < 128) {
        const float* wp = W + (size_t)n * 256 + kg * 8;
        float4 v0 = *(const float4*)wp;
        float4 v1 = *(const float4*)(wp + 4);
        v[0] = v0.x; v[1] = v0.y; v[2] = v0.z; v[3] = v0.w;
        v[4] = v1.x; v[5] = v1.y; v[6] = v1.z; v[7] = v1.w;
    } else if (n < 136) {
        int i = n - 128, hh = i & 3, lr = i >> 2;
        const float* av = lr ? ar : al;
#pragma unroll
        for (int j = 0; j < 8; j++) v[j] = 0.f;
        for (int c = 0; c < 32; c++) {
            float a = av[hh * 32 + c];
            const float* wp = W + (size_t)(hh * 32 + c) * 256 + kg * 8;
#pragma unroll
            for (int j = 0; j < 8; j++) v[j] += a * wp[j];
        }
    } else {
#pragma unroll
        for (int j = 0; j < 8; j++) v[j] = 0.f;
    }
    short s8[8];
#pragma unroll
    for (int j = 0; j < 8; j++) s8[j] = (short)f2bf(v[j]);
    int kstep = kg >> 2, ntile = n >> 4;
    int L     = (kg & 3) * 16 + (n & 15);
    int slot  = kstep * 9 + ntile;
    *(short8v*)&wfrag[(slot * 64 + L) * 8] = *(short8v*)s8;
}

// ---------------- MFMA GEMM + fused el/er ------------------------------------
// block = 256 thr (4 waves); tile 64 nodes x 128 outs; wave = 16 rows.
// W ntiles 0..7 staged linearly into 64 KB LDS; ntile 8 (attn cols) read from
// global (8 KB, L2-resident). Wave's whole A-slice (16 dwordx4/lane) issued
// up-front so HBM latency is paid once, not per-ks.
__global__ __launch_bounds__(256) void k_gemm(const float* __restrict__ feat,
                                              const short* __restrict__ wfrag,
                                              unsigned short* __restrict__ hb,
                                              float* __restrict__ el,
                                              float* __restrict__ er, int N) {
    __shared__ short wlds[32768];   // 64 KB: slots ks*8+nt (nt<8)
    const int t    = threadIdx.x;
    const int lane = t & 63;
    const int wave = t >> 6;
    const int n0   = blockIdx.x * 64;
    const int g    = lane >> 4;     // k-quad
    const int c    = lane & 15;

    // ---- stage W ntiles 0..7: linear 16 B chunks, skip every 9th slot
#pragma unroll
    for (int i = 0; i < 16; i++) {
        int p  = t + i * 256;                   // chunk 0..4095
        int sl = p >> 6, li = p & 63;           // lds slot, lane-in-slot
        int gs = (sl >> 3) * 9 + (sl & 7);      // global slot
        *(short8v*)&wlds[(size_t)p * 8] =
            *(const short8v*)&wfrag[((size_t)gs * 64 + li) * 8];
    }

    // ---- issue the wave's entire A slice (before the barrier: independent)
    const int row = n0 + wave * 16 + c;
    const int rc  = row < N ? row : N - 1;
    const float* ap = feat + (size_t)rc * 256 + g * 8;
    float4 a4[16];
#pragma unroll
    for (int ks = 0; ks < 8; ks++) {
        a4[2 * ks]     = *(const float4*)(ap + ks * 32);
        a4[2 * ks + 1] = *(const float4*)(ap + ks * 32 + 4);
    }

    __syncthreads();

    f32x4 acc[9];
#pragma unroll
    for (int nt = 0; nt < 9; nt++) acc[nt] = (f32x4){0.f, 0.f, 0.f, 0.f};

#pragma unroll
    for (int ks = 0; ks < 8; ks++) {
        float4 v0 = a4[2 * ks], v1 = a4[2 * ks + 1];
        short s8[8];
        s8[0] = (short)f2bf(v0.x); s8[1] = (short)f2bf(v0.y);
        s8[2] = (short)f2bf(v0.z); s8[3] = (short)f2bf(v0.w);
        s8[4] = (short)f2bf(v1.x); s8[5] = (short)f2bf(v1.y);
        s8[6] = (short)f2bf(v1.z); s8[7] = (short)f2bf(v1.w);
        short8v afrag = *(short8v*)s8;
        // attn ntile from global (L1/L2-resident 8 KB)
        short8v b8 = *(const short8v*)&wfrag[(((size_t)ks * 9 + 8) * 64 + lane) * 8];
#pragma unroll
        for (int nt = 0; nt < 8; nt++) {
            short8v b = *(short8v*)&wlds[(((size_t)ks * 8 + nt) * 64 + lane) * 8];
            acc[nt] = __builtin_amdgcn_mfma_f32_16x16x32_bf16(afrag, b, acc[nt], 0, 0, 0);
        }
        acc[8] = __builtin_amdgcn_mfma_f32_16x16x32_bf16(afrag, b8, acc[8], 0, 0, 0);
    }

    // ---- epilogue: C/D layout col = nt*16 + c, row = wave*16 + g*4 + r
#pragma unroll
    for (int r = 0; r < 4; r++) {
        int m = n0 + wave * 16 + g * 4 + r;
        if (m < N) {
#pragma unroll
            for (int nt = 0; nt < 8; nt++)
                hb[(size_t)m * 128 + nt * 16 + c] = f2bf(acc[nt][r]);
            // attn tile: cols 0..3 = el heads, 4..7 = er heads
            float av = acc[8][r];
            if (c < 4)      el[(size_t)m * 4 + c]       = av;
            else if (c < 8) er[(size_t)m * 4 + (c - 4)] = av;
        }
    }
}

// ---------------- bucketed CSR build -----------------------------------------
// Buckets of 256 consecutive dst nodes (NB = ceil(N/256) <= 512 for this
// problem).  Replaces per-edge random atomics + 17x-amplified random 4B
// writes with: per-WG LDS histograms + ~NB aggregated global atomics per WG,
// then per-bucket CSR finalize where each WG owns a ~10 KB contiguous CSR
// segment (lines fully populated in L2 before eviction).
#define NPB_SHIFT 8
#define BIN_EPT   16
#define BIN_EDGES (256 * BIN_EPT)   // 4096 edges per WG

__global__ __launch_bounds__(256) void k_binhist(const int* __restrict__ dst,
                                                 int* __restrict__ bcount,
                                                 int E, int NB) {
    __shared__ int hist[512];
    int t = threadIdx.x;
    for (int i = t; i < NB; i += 256) hist[i] = 0;
    __syncthreads();
    int base = blockIdx.x * BIN_EDGES + t;
#pragma unroll
    for (int k = 0; k < BIN_EPT; k++) {
        int idx = base + k * 256;
        if (idx < E) atomicAdd(&hist[dst[idx] >> NPB_SHIFT], 1);
    }
    __syncthreads();
    for (int i = t; i < NB; i += 256) {
        int h = hist[i];
        if (h) atomicAdd(&bcount[i], h);
    }
}

// single-WG scan of bucket counts -> bucket bases (== CSR bases) + cursors
__global__ __launch_bounds__(512) void k_bscan(const int* __restrict__ bcount,
                                               int* __restrict__ bbase,
                                               int* __restrict__ bcur, int NB) {
    __shared__ int s[512];
    int t = threadIdx.x;
    int h = (t < NB) ? bcount[t] : 0;
    s[t] = h;
    __syncthreads();
    for (int off = 1; off < 512; off <<= 1) {
        int v = (t >= off) ? s[t - off] : 0;
        __syncthreads();
        s[t] += v;
        __syncthreads();
    }
    int excl = s[t] - h;
    if (t <= NB) bbase[t] = excl;     // bbase[NB] = E
    if (t < NB)  bcur[t]  = excl;
}

__global__ __launch_bounds__(256) void k_binscatter(const int* __restrict__ src,
                                                    const int* __restrict__ dst,
                                                    int* __restrict__ bcur,
                                                    int2* __restrict__ binned,
                                                    int E, int NB) {
    __shared__ int hist[512];
    __shared__ int cur[512];
    int t = threadIdx.x;
    for (int i = t; i < NB; i += 256) hist[i] = 0;
    __syncthreads();
    int base = blockIdx.x * BIN_EDGES + t;
    int sv[BIN_EPT], dv[BIN_EPT];
#pragma unroll
    for (int k = 0; k < BIN_EPT; k++) {
        int idx = base + k * 256;
        if (idx < E) {
            sv[k] = src[idx];
            dv[k] = dst[idx];
            atomicAdd(&hist[dv[k] >> NPB_SHIFT], 1);
        } else {
            dv[k] = -1;
        }
    }
    __syncthreads();
    // one global atomic per (WG, bucket) claims a contiguous range
    for (int i = t; i < NB; i += 256) {
        int h = hist[i];
        cur[i] = h ? atomicAdd(&bcur[i], h) : 0;
    }
    __syncthreads();
#pragma unroll
    for (int k = 0; k < BIN_EPT; k++) {
        if (dv[k] >= 0) {
            int p = atomicAdd(&cur[dv[k] >> NPB_SHIFT], 1);
            binned[p] = make_int2(sv[k], dv[k]);
        }
    }
}

// one WG per bucket: local degree histogram -> deg/start, then scatter src
// into the bucket's private contiguous CSR segment.
__global__ __launch_bounds__(256) void k_csr(const int2* __restrict__ binned,
                                             const int* __restrict__ bbase,
                                             int* __restrict__ startA,
                                             int* __restrict__ deg,
                                             int* __restrict__ src_csr, int N) {
    __shared__ int hist[256];
    __shared__ int scn[256];
    __shared__ int cur[256];
    int b = blockIdx.x;
    int t = threadIdx.x;
    int base = bbase[b];
    int cnt  = bbase[b + 1] - base;
    int node0 = b << NPB_SHIFT;
    hist[t] = 0;
    __syncthreads();
    for (int i = t; i < cnt; i += 256) {
        int2 e = binned[base + i];
        atomicAdd(&hist[e.y - node0], 1);
    }
    __syncthreads();
    int h = hist[t];
    scn[t] = h;
    __syncthreads();
    for (int off = 1; off < 256; off <<= 1) {
        int v = (t >= off) ? scn[t - off] : 0;
        __syncthreads();
        scn[t] += v;
        __syncthreads();
    }
    int excl  = scn[t] - h;
    int gnode = node0 + t;
    if (gnode < N) { deg[gnode] = h; startA[gnode] = base + excl; }
    cur[t] = excl;
    __syncthreads();
    for (int i = t; i < cnt; i += 256) {
        int2 e = binned[base + i];
        int p = atomicAdd(&cur[e.y - node0], 1);
        src_csr[base + p] = e.x;
    }
}

// ---------------- gather-side aggregation: one wave per dst node -------------
// w_e = exp(leaky(el[src_e] + er[n])) computed in-kernel (el/er L2-resident;
// er[n] wave-uniform).  out[n] = bias + hb[n]*Σ hb[src] + (Σ w hb[src]) / Σ w
__global__ __launch_bounds__(256) void k_agg(
        const unsigned int* __restrict__ hbu,
        const float* __restrict__ el, const float* __restrict__ er,
        const int* __restrict__ src_csr,
        const int* __restrict__ start, const int* __restrict__ deg,
        const float* __restrict__ bias, float* __restrict__ out, int N) {
    int wid  = blockIdx.x * 4 + (threadIdx.x >> 6);
    int lane = threadIdx.x & 63;
    if (wid >= N) return;
    int beg = __builtin_amdgcn_readfirstlane(start[wid]);
    int dg  = __builtin_amdgcn_readfirstlane(deg[wid]);
    int head = lane >> 4;   // elements (2*lane, 2*lane+1) share one head

    float er_own = er[(size_t)wid * 4 + head];   // wave-uniform per 16-lane group

    float S1x = 0.f, S1y = 0.f, S2x = 0.f, S2y = 0.f, dd = 0.f;
    int i = 0;
    for (; i + 4 <= dg; i += 4) {
        int b = beg + i;
        int s0 = src_csr[b], s1 = src_csr[b + 1], s2 = src_csr[b + 2], s3 = src_csr[b + 3];
        unsigned int u0 = hbu[(size_t)s0 * 64 + lane];
        unsigned int u1 = hbu[(size_t)s1 * 64 + lane];
        unsigned int u2 = hbu[(size_t)s2 * 64 + lane];
        unsigned int u3 = hbu[(size_t)s3 * 64 + lane];
        float t0 = el[(size_t)s0 * 4 + head] + er_own;
        float t1 = el[(size_t)s1 * 4 + head] + er_own;
        float t2 = el[(size_t)s2 * 4 + head] + er_own;
        float t3 = el[(size_t)s3 * 4 + head] + er_own;
        t0 = t0 > 0.f ? t0 : NEG_SLOPE * t0;
        t1 = t1 > 0.f ? t1 : NEG_SLOPE * t1;
        t2 = t2 > 0.f ? t2 : NEG_SLOPE * t2;
        t3 = t3 > 0.f ? t3 : NEG_SLOPE * t3;
        float w0 = __expf(t0), w1 = __expf(t1), w2 = __expf(t2), w3 = __expf(t3);
        float x0 = uas(u0 << 16), y0 = uas(u0 & 0xFFFF0000u);
        float x1 = uas(u1 << 16), y1 = uas(u1 & 0xFFFF0000u);
        float x2 = uas(u2 << 16), y2 = uas(u2 & 0xFFFF0000u);
        float x3 = uas(u3 << 16), y3 = uas(u3 & 0xFFFF0000u);
        S1x += (x0 + x1) + (x2 + x3);
        S1y += (y0 + y1) + (y2 + y3);
        S2x += w0 * x0 + w1 * x1 + w2 * x2 + w3 * x3;
        S2y += w0 * y0 + w1 * y1 + w2 * y2 + w3 * y3;
        dd  += (w0 + w1) + (w2 + w3);
    }
    for (; i < dg; i++) {
        int b = beg + i;
        int s0 = src_csr[b];
        unsigned int u0 = hbu[(size_t)s0 * 64 + lane];
        float t0 = el[(size_t)s0 * 4 + head] + er_own;
        t0 = t0 > 0.f ? t0 : NEG_SLOPE * t0;
        float w0 = __expf(t0);
        float x0 = uas(u0 << 16), y0 = uas(u0 & 0xFFFF0000u);
        S1x += x0; S1y += y0;
        S2x += w0 * x0; S2y += w0 * y0;
        dd  += w0;
    }

    unsigned int uh = hbu[(size_t)wid * 64 + lane];
    float hvx = uas(uh << 16), hvy = uas(uh & 0xFFFF0000u);
    float2 bv = ((const float2*)bias)[lane];
    float inv = dd > 0.f ? 1.f / dd : 0.f;
    float ox = bv.x + hvx * S1x + S2x * inv;
    float oy = bv.y + hvy * S1y + S2y * inv;
    float2 o = {ox, oy};
    ((float2*)(out + (size_t)wid * 128))[lane] = o;
}

extern "C" void kernel_launch(void* const* d_in, const int* in_sizes, int n_in,
                              void* d_out, int out_size, void* d_ws, size_t ws_size,
                              hipStream_t stream) {
    const float* feat = (const float*)d_in[0];
    const float* W_fc = (const float*)d_in[1];
    const float* al   = (const float*)d_in[2];
    const float* ar   = (const float*)d_in[3];
    const float* bias = (const float*)d_in[4];
    const int*   src  = (const int*)d_in[5];
    const int*   dst  = (const int*)d_in[6];
    const int N = in_sizes[0] / 256;
    const int E = in_sizes[5];
    const int NB = (N + 255) >> NPB_SHIFT;   // <= 512 for N <= 131072

    char* ws = (char*)d_ws;
    size_t off = 0;
    unsigned int* hbu = (unsigned int*)(ws + off); off += (size_t)N * 64 * 4; // 25.6 MB
    float* el         = (float*)(ws + off); off += (size_t)N * 4 * 4;         // 1.6 MB
    float* er         = (float*)(ws + off); off += (size_t)N * 4 * 4;         // 1.6 MB
    int* deg          = (int*)(ws + off);   off += (size_t)N * 4;
    int* startA       = (int*)(ws + off);   off += (size_t)N * 4;
    int* src_csr      = (int*)(ws + off);   off += (size_t)E * 4;             // 4 MB
    int2* binned      = (int2*)(ws + off);  off += (size_t)E * 8;             // 8 MB
    short* wfrag      = (short*)(ws + off); off += (size_t)72 * 64 * 8 * 2;   // 72 KB
    int* bcount       = (int*)(ws + off);   off += 2048;
    int* bbase        = (int*)(ws + off);   off += 2064;                      // NB+1
    int* bcur         = (int*)(ws + off);   off += 2048;

    float* out = (float*)d_out;

    hipMemsetAsync(bcount, 0, (size_t)NB * 4, stream);
    k_prep<<<18, 256, 0, stream>>>(W_fc, al, ar, wfrag);
    k_gemm<<<(N + 63) / 64, 256, 0, stream>>>(feat, wfrag, (unsigned short*)hbu,
                                              el, er, N);
    int binWG = (E + BIN_EDGES - 1) / BIN_EDGES;
    k_binhist<<<binWG, 256, 0, stream>>>(dst, bcount, E, NB);
    k_bscan<<<1, 512, 0, stream>>>(bcount, bbase, bcur, NB);
    k_binscatter<<<binWG, 256, 0, stream>>>(src, dst, bcur, binned, E, NB);
    k_csr<<<NB, 256, 0, stream>>>(binned, bbase, startA, deg, src_csr, N);
    k_agg<<<(N + 3) / 4, 256, 0, stream>>>(hbu, el, er, src_csr, startA, deg,
                                           bias, out, N);
}

// Round 2
// 273.747 us; speedup vs baseline: 1.3740x; 1.0619x over previous
//
#include <hip/hip_runtime.h>
#include <hip/hip_bf16.h>
#include <hip/hip_fp16.h>
#include <math.h>

#define NEG_SLOPE 0.2f

typedef __attribute__((ext_vector_type(8))) short short8v;
typedef __attribute__((ext_vector_type(4))) float f32x4;

__device__ __forceinline__ float uas(unsigned int u) { return __uint_as_float(u); }

__device__ __forceinline__ unsigned short f2bf(float x) {
    __hip_bfloat16 b = __float2bfloat16(x);
    return *(unsigned short*)&b;
}

#define NPB_SHIFT 8
#define BIN_EPT   16
#define BIN_EDGES (256 * BIN_EPT)   // 4096 edges per histogram slice

// ---------------- W prep: extended bf16 fragment image -----------------------
// Extended B matrix W'[144,256]: rows 0..127 = W; rows 128..135 = head-masked
// attn projections vl[4],vr[4]; rows 136..143 = 0.  Fragment layout (9 ntiles):
//   slot(kstep,ntile) = kstep*9+ntile; lane L=(kg&3)*16+(n&15) holds 8 shorts
//   B'[n][k=kstep*32+(L>>4)*8+j]  -> lane-contiguous 16 B.
// Also zeroes bcount (replaces a hipMemsetAsync dispatch).
__global__ void k_prep(const float* __restrict__ W, const float* __restrict__ al,
                       const float* __restrict__ ar, short* __restrict__ wfrag,
                       int* __restrict__ bcount, int NB) {
    int p = blockIdx.x * 256 + threadIdx.x;   // n*32+kg, 0..4607
    if (p < NB) bcount[p] = 0;
    if (p >= 144 * 32) return;
    int n = p >> 5, kg = p & 31;
    float v[8];
    if (n < 128) {
        const float* wp = W + (size_t)n * 256 + kg * 8;
        float4 v0 = *(const float4*)wp;
        float4 v1 = *(const float4*)(wp + 4);
        v[0] = v0.x; v[1] = v0.y; v[2] = v0.z; v[3] = v0.w;
        v[4] = v1.x; v[5] = v1.y; v[6] = v1.z; v[7] = v1.w;
    } else if (n < 136) {
        int i = n - 128, hh = i & 3, lr = i >> 2;
        const float* av = lr ? ar : al;
#pragma unroll
        for (int j = 0; j < 8; j++) v[j] = 0.f;
        for (int c = 0; c < 32; c++) {
            float a = av[hh * 32 + c];
            const float* wp = W + (size_t)(hh * 32 + c) * 256 + kg * 8;
#pragma unroll
            for (int j = 0; j < 8; j++) v[j] += a * wp[j];
        }
    } else {
#pragma unroll
        for (int j = 0; j < 8; j++) v[j] = 0.f;
    }
    short s8[8];
#pragma unroll
    for (int j = 0; j < 8; j++) s8[j] = (short)f2bf(v[j]);
    int kstep = kg >> 2, ntile = n >> 4;
    int L     = (kg & 3) * 16 + (n & 15);
    int slot  = kstep * 9 + ntile;
    *(short8v*)&wfrag[(slot * 64 + L) * 8] = *(short8v*)s8;
}

// ---------------- MFMA GEMM + fused el/er + fused bucket histogram -----------
// block = 256 thr (4 waves); tile 64 nodes x 128 outs; wave = 16 rows.
// W ntiles 0..7 staged linearly into 64 KB LDS; ntile 8 (attn cols) read from
// global (8 KB, L2-resident). Wave's whole A-slice (16 dwordx4/lane) issued
// up-front so HBM latency is paid once, not per-ks.
// Blocks with blockIdx.x*BIN_EDGES < E additionally histogram a 4096-edge
// slice of dst into buckets (LDS hist + <=NB aggregated global atomics) --
// this absorbs the former k_binhist dispatch into gemm's latency slack.
__global__ __launch_bounds__(256) void k_gemm(const float* __restrict__ feat,
                                              const short* __restrict__ wfrag,
                                              unsigned short* __restrict__ hb,
                                              float* __restrict__ el,
                                              float* __restrict__ er, int N,
                                              const int* __restrict__ dst,
                                              int* __restrict__ bcount,
                                              int E, int NB) {
    __shared__ short wlds[32768];   // 64 KB: slots ks*8+nt (nt<8)
    __shared__ int bh[512];         // bucket histogram
    const int t    = threadIdx.x;
    const int lane = t & 63;
    const int wave = t >> 6;
    const int n0   = blockIdx.x * 64;
    const int g    = lane >> 4;     // k-quad
    const int c    = lane & 15;
    const bool do_hist = (blockIdx.x * BIN_EDGES) < E;

    if (do_hist) {
        for (int i = t; i < 512; i += 256) bh[i] = 0;
    }

    // ---- stage W ntiles 0..7: linear 16 B chunks, skip every 9th slot
#pragma unroll
    for (int i = 0; i < 16; i++) {
        int p  = t + i * 256;                   // chunk 0..4095
        int sl = p >> 6, li = p & 63;           // lds slot, lane-in-slot
        int gs = (sl >> 3) * 9 + (sl & 7);      // global slot
        *(short8v*)&wlds[(size_t)p * 8] =
            *(const short8v*)&wfrag[((size_t)gs * 64 + li) * 8];
    }

    // ---- issue the wave's entire A slice (before the barrier: independent)
    const int row = n0 + wave * 16 + c;
    const int rc  = row < N ? row : N - 1;
    const float* ap = feat + (size_t)rc * 256 + g * 8;
    float4 a4[16];
#pragma unroll
    for (int ks = 0; ks < 8; ks++) {
        a4[2 * ks]     = *(const float4*)(ap + ks * 32);
        a4[2 * ks + 1] = *(const float4*)(ap + ks * 32 + 4);
    }

    __syncthreads();

    f32x4 acc[9];
#pragma unroll
    for (int nt = 0; nt < 9; nt++) acc[nt] = (f32x4){0.f, 0.f, 0.f, 0.f};

#pragma unroll
    for (int ks = 0; ks < 8; ks++) {
        float4 v0 = a4[2 * ks], v1 = a4[2 * ks + 1];
        short s8[8];
        s8[0] = (short)f2bf(v0.x); s8[1] = (short)f2bf(v0.y);
        s8[2] = (short)f2bf(v0.z); s8[3] = (short)f2bf(v0.w);
        s8[4] = (short)f2bf(v1.x); s8[5] = (short)f2bf(v1.y);
        s8[6] = (short)f2bf(v1.z); s8[7] = (short)f2bf(v1.w);
        short8v afrag = *(short8v*)s8;
        // attn ntile from global (L1/L2-resident 8 KB)
        short8v b8 = *(const short8v*)&wfrag[(((size_t)ks * 9 + 8) * 64 + lane) * 8];
#pragma unroll
        for (int nt = 0; nt < 8; nt++) {
            short8v b = *(short8v*)&wlds[(((size_t)ks * 8 + nt) * 64 + lane) * 8];
            acc[nt] = __builtin_amdgcn_mfma_f32_16x16x32_bf16(afrag, b, acc[nt], 0, 0, 0);
        }
        acc[8] = __builtin_amdgcn_mfma_f32_16x16x32_bf16(afrag, b8, acc[8], 0, 0, 0);
    }

    // ---- epilogue: C/D layout col = nt*16 + c, row = wave*16 + g*4 + r
#pragma unroll
    for (int r = 0; r < 4; r++) {
        int m = n0 + wave * 16 + g * 4 + r;
        if (m < N) {
#pragma unroll
            for (int nt = 0; nt < 8; nt++)
                hb[(size_t)m * 128 + nt * 16 + c] = f2bf(acc[nt][r]);
            // attn tile: cols 0..3 = el heads, 4..7 = er heads
            float av = acc[8][r];
            if (c < 4)      el[(size_t)m * 4 + c]       = av;
            else if (c < 8) er[(size_t)m * 4 + (c - 4)] = av;
        }
    }

    // ---- fused bucket histogram (slice of 4096 edges)
    if (do_hist) {
        int base = blockIdx.x * BIN_EDGES + t;
#pragma unroll
        for (int k = 0; k < BIN_EPT; k++) {
            int idx = base + k * 256;
            if (idx < E) atomicAdd(&bh[dst[idx] >> NPB_SHIFT], 1);
        }
        __syncthreads();
        for (int i = t; i < NB; i += 256) {
            int h = bh[i];
            if (h) atomicAdd(&bcount[i], h);
        }
    }
}

// single-WG scan of bucket counts -> bucket bases (== CSR bases) + cursors
__global__ __launch_bounds__(512) void k_bscan(const int* __restrict__ bcount,
                                               int* __restrict__ bbase,
                                               int* __restrict__ bcur, int NB) {
    __shared__ int s[512];
    int t = threadIdx.x;
    int h = (t < NB) ? bcount[t] : 0;
    s[t] = h;
    __syncthreads();
    for (int off = 1; off < 512; off <<= 1) {
        int v = (t >= off) ? s[t - off] : 0;
        __syncthreads();
        s[t] += v;
        __syncthreads();
    }
    int excl = s[t] - h;
    if (t <= NB) bbase[t] = excl;     // bbase[NB] = E
    if (t < NB)  bcur[t]  = excl;
}

// scatter edges into bucket-contiguous order, packed src|ldst<<24 (4 B/edge)
__global__ __launch_bounds__(256) void k_binscatter(const int* __restrict__ src,
                                                    const int* __restrict__ dst,
                                                    int* __restrict__ bcur,
                                                    unsigned int* __restrict__ binned,
                                                    int E, int NB) {
    __shared__ int hist[512];
    __shared__ int cur[512];
    int t = threadIdx.x;
    for (int i = t; i < NB; i += 256) hist[i] = 0;
    __syncthreads();
    int base = blockIdx.x * BIN_EDGES + t;
    int sv[BIN_EPT], dv[BIN_EPT];
#pragma unroll
    for (int k = 0; k < BIN_EPT; k++) {
        int idx = base + k * 256;
        if (idx < E) {
            sv[k] = src[idx];
            dv[k] = dst[idx];
            atomicAdd(&hist[dv[k] >> NPB_SHIFT], 1);
        } else {
            dv[k] = -1;
        }
    }
    __syncthreads();
    // one global atomic per (WG, bucket) claims a contiguous range
    for (int i = t; i < NB; i += 256) {
        int h = hist[i];
        cur[i] = h ? atomicAdd(&bcur[i], h) : 0;
    }
    __syncthreads();
#pragma unroll
    for (int k = 0; k < BIN_EPT; k++) {
        if (dv[k] >= 0) {
            int p = atomicAdd(&cur[dv[k] >> NPB_SHIFT], 1);
            binned[p] = (unsigned int)sv[k] | ((unsigned int)(dv[k] & 255) << 24);
        }
    }
}

// one WG per bucket: local degree histogram -> deg/start, then scatter src
// into the bucket's private contiguous CSR segment.
__global__ __launch_bounds__(256) void k_csr(const unsigned int* __restrict__ binned,
                                             const int* __restrict__ bbase,
                                             int* __restrict__ startA,
                                             int* __restrict__ deg,
                                             int* __restrict__ src_csr, int N) {
    __shared__ int hist[256];
    __shared__ int scn[256];
    __shared__ int cur[256];
    int b = blockIdx.x;
    int t = threadIdx.x;
    int base = bbase[b];
    int cnt  = bbase[b + 1] - base;
    int node0 = b << NPB_SHIFT;
    hist[t] = 0;
    __syncthreads();
    for (int i = t; i < cnt; i += 256) {
        unsigned int e = binned[base + i];
        atomicAdd(&hist[e >> 24], 1);
    }
    __syncthreads();
    int h = hist[t];
    scn[t] = h;
    __syncthreads();
    for (int off = 1; off < 256; off <<= 1) {
        int v = (t >= off) ? scn[t - off] : 0;
        __syncthreads();
        scn[t] += v;
        __syncthreads();
    }
    int excl  = scn[t] - h;
    int gnode = node0 + t;
    if (gnode < N) { deg[gnode] = h; startA[gnode] = base + excl; }
    cur[t] = excl;
    __syncthreads();
    for (int i = t; i < cnt; i += 256) {
        unsigned int e = binned[base + i];
        int p = atomicAdd(&cur[e >> 24], 1);
        src_csr[base + p] = (int)(e & 0xFFFFFFu);
    }
}

// ---------------- gather-side aggregation: one wave per dst node -------------
// w_e = exp(leaky(el[src_e] + er[n])) computed in-kernel (el/er L2-resident;
// er[n] wave-uniform).  out[n] = bias + hb[n]*Σ hb[src] + (Σ w hb[src]) / Σ w
__global__ __launch_bounds__(256) void k_agg(
        const unsigned int* __restrict__ hbu,
        const float* __restrict__ el, const float* __restrict__ er,
        const int* __restrict__ src_csr,
        const int* __restrict__ start, const int* __restrict__ deg,
        const float* __restrict__ bias, float* __restrict__ out, int N) {
    int wid  = blockIdx.x * 4 + (threadIdx.x >> 6);
    int lane = threadIdx.x & 63;
    if (wid >= N) return;
    int beg = __builtin_amdgcn_readfirstlane(start[wid]);
    int dg  = __builtin_amdgcn_readfirstlane(deg[wid]);
    int head = lane >> 4;   // elements (2*lane, 2*lane+1) share one head

    float er_own = er[(size_t)wid * 4 + head];   // wave-uniform per 16-lane group

    float S1x = 0.f, S1y = 0.f, S2x = 0.f, S2y = 0.f, dd = 0.f;
    int i = 0;
    for (; i + 4 <= dg; i += 4) {
        int b = beg + i;
        int s0 = src_csr[b], s1 = src_csr[b + 1], s2 = src_csr[b + 2], s3 = src_csr[b + 3];
        unsigned int u0 = hbu[(size_t)s0 * 64 + lane];
        unsigned int u1 = hbu[(size_t)s1 * 64 + lane];
        unsigned int u2 = hbu[(size_t)s2 * 64 + lane];
        unsigned int u3 = hbu[(size_t)s3 * 64 + lane];
        float t0 = el[(size_t)s0 * 4 + head] + er_own;
        float t1 = el[(size_t)s1 * 4 + head] + er_own;
        float t2 = el[(size_t)s2 * 4 + head] + er_own;
        float t3 = el[(size_t)s3 * 4 + head] + er_own;
        t0 = t0 > 0.f ? t0 : NEG_SLOPE * t0;
        t1 = t1 > 0.f ? t1 : NEG_SLOPE * t1;
        t2 = t2 > 0.f ? t2 : NEG_SLOPE * t2;
        t3 = t3 > 0.f ? t3 : NEG_SLOPE * t3;
        float w0 = __expf(t0), w1 = __expf(t1), w2 = __expf(t2), w3 = __expf(t3);
        float x0 = uas(u0 << 16), y0 = uas(u0 & 0xFFFF0000u);
        float x1 = uas(u1 << 16), y1 = uas(u1 & 0xFFFF0000u);
        float x2 = uas(u2 << 16), y2 = uas(u2 & 0xFFFF0000u);
        float x3 = uas(u3 << 16), y3 = uas(u3 & 0xFFFF0000u);
        S1x += (x0 + x1) + (x2 + x3);
        S1y += (y0 + y1) + (y2 + y3);
        S2x += w0 * x0 + w1 * x1 + w2 * x2 + w3 * x3;
        S2y += w0 * y0 + w1 * y1 + w2 * y2 + w3 * y3;
        dd  += (w0 + w1) + (w2 + w3);
    }
    for (; i < dg; i++) {
        int b = beg + i;
        int s0 = src_csr[b];
        unsigned int u0 = hbu[(size_t)s0 * 64 + lane];
        float t0 = el[(size_t)s0 * 4 + head] + er_own;
        t0 = t0 > 0.f ? t0 : NEG_SLOPE * t0;
        float w0 = __expf(t0);
        float x0 = uas(u0 << 16), y0 = uas(u0 & 0xFFFF0000u);
        S1x += x0; S1y += y0;
        S2x += w0 * x0; S2y += w0 * y0;
        dd  += w0;
    }

    unsigned int uh = hbu[(size_t)wid * 64 + lane];
    float hvx = uas(uh << 16), hvy = uas(uh & 0xFFFF0000u);
    float2 bv = ((const float2*)bias)[lane];
    float inv = dd > 0.f ? 1.f / dd : 0.f;
    float ox = bv.x + hvx * S1x + S2x * inv;
    float oy = bv.y + hvy * S1y + S2y * inv;
    float2 o = {ox, oy};
    ((float2*)(out + (size_t)wid * 128))[lane] = o;
}

extern "C" void kernel_launch(void* const* d_in, const int* in_sizes, int n_in,
                              void* d_out, int out_size, void* d_ws, size_t ws_size,
                              hipStream_t stream) {
    const float* feat = (const float*)d_in[0];
    const float* W_fc = (const float*)d_in[1];
    const float* al   = (const float*)d_in[2];
    const float* ar   = (const float*)d_in[3];
    const float* bias = (const float*)d_in[4];
    const int*   src  = (const int*)d_in[5];
    const int*   dst  = (const int*)d_in[6];
    const int N = in_sizes[0] / 256;
    const int E = in_sizes[5];
    const int NB = (N + 255) >> NPB_SHIFT;   // <= 512 for N <= 131072

    char* ws = (char*)d_ws;
    size_t off = 0;
    unsigned int* hbu = (unsigned int*)(ws + off); off += (size_t)N * 64 * 4; // 25.6 MB
    float* el         = (float*)(ws + off); off += (size_t)N * 4 * 4;         // 1.6 MB
    float* er         = (float*)(ws + off); off += (size_t)N * 4 * 4;         // 1.6 MB
    int* deg          = (int*)(ws + off);   off += (size_t)N * 4;
    int* startA       = (int*)(ws + off);   off += (size_t)N * 4;
    int* src_csr      = (int*)(ws + off);   off += (size_t)E * 4;             // 4 MB
    unsigned int* binned = (unsigned int*)(ws + off); off += (size_t)E * 4;   // 4 MB
    short* wfrag      = (short*)(ws + off); off += (size_t)72 * 64 * 8 * 2;   // 72 KB
    int* bcount       = (int*)(ws + off);   off += 2048;
    int* bbase        = (int*)(ws + off);   off += 2064;                      // NB+1
    int* bcur         = (int*)(ws + off);   off += 2048;

    float* out = (float*)d_out;

    k_prep<<<18, 256, 0, stream>>>(W_fc, al, ar, wfrag, bcount, NB);
    k_gemm<<<(N + 63) / 64, 256, 0, stream>>>(feat, wfrag, (unsigned short*)hbu,
                                              el, er, N, dst, bcount, E, NB);
    int binWG = (E + BIN_EDGES - 1) / BIN_EDGES;
    k_bscan<<<1, 512, 0, stream>>>(bcount, bbase, bcur, NB);
    k_binscatter<<<binWG, 256, 0, stream>>>(src, dst, bcur, binned, E, NB);
    k_csr<<<NB, 256, 0, stream>>>(binned, bbase, startA, deg, src_csr, N);
    k_agg<<<(N + 3) / 4, 256, 0, stream>>>(hbu, el, er, src_csr, startA, deg,
                                           bias, out, N);
}

// Round 4
// 273.298 us; speedup vs baseline: 1.3763x; 1.0016x over previous
//
#include <hip/hip_runtime.h>
#include <hip/hip_bf16.h>
#include <hip/hip_fp16.h>
#include <math.h>

#define NEG_SLOPE 0.2f

typedef __attribute__((ext_vector_type(8))) short short8v;
typedef __attribute__((ext_vector_type(4))) float f32x4;

__device__ __forceinline__ float uas(unsigned int u) { return __uint_as_float(u); }

__device__ __forceinline__ unsigned short f2bf(float x) {
    __hip_bfloat16 b = __float2bfloat16(x);
    return *(unsigned short*)&b;
}

#define NPB_SHIFT 8
#define BIN_EPT   16
#define BIN_EDGES (256 * BIN_EPT)   // 4096 edges per histogram slice

// ---------------- W prep: extended bf16 fragment image -----------------------
// Extended B matrix W'[144,256]: rows 0..127 = W; rows 128..135 = head-masked
// attn projections vl[4],vr[4]; rows 136..143 = 0.  Also zeroes bcount.
__global__ void k_prep(const float* __restrict__ W, const float* __restrict__ al,
                       const float* __restrict__ ar, short* __restrict__ wfrag,
                       int* __restrict__ bcount, int NB) {
    int p = blockIdx.x * 256 + threadIdx.x;   // n*32+kg, 0..4607
    if (p < NB) bcount[p] = 0;
    if (p >= 144 * 32) return;
    int n = p >> 5, kg = p & 31;
    float v[8];
    if (n < 128) {
        const float* wp = W + (size_t)n * 256 + kg * 8;
        float4 v0 = *(const float4*)wp;
        float4 v1 = *(const float4*)(wp + 4);
        v[0] = v0.x; v[1] = v0.y; v[2] = v0.z; v[3] = v0.w;
        v[4] = v1.x; v[5] = v1.y; v[6] = v1.z; v[7] = v1.w;
    } else if (n < 136) {
        int i = n - 128, hh = i & 3, lr = i >> 2;
        const float* av = lr ? ar : al;
#pragma unroll
        for (int j = 0; j < 8; j++) v[j] = 0.f;
        for (int c = 0; c < 32; c++) {
            float a = av[hh * 32 + c];
            const float* wp = W + (size_t)(hh * 32 + c) * 256 + kg * 8;
#pragma unroll
            for (int j = 0; j < 8; j++) v[j] += a * wp[j];
        }
    } else {
#pragma unroll
        for (int j = 0; j < 8; j++) v[j] = 0.f;
    }
    short s8[8];
#pragma unroll
    for (int j = 0; j < 8; j++) s8[j] = (short)f2bf(v[j]);
    int kstep = kg >> 2, ntile = n >> 4;
    int L     = (kg & 3) * 16 + (n & 15);
    int slot  = kstep * 9 + ntile;
    *(short8v*)&wfrag[(slot * 64 + L) * 8] = *(short8v*)s8;
}

// ---------------- MFMA GEMM + fused el/er + fused bucket histogram -----------
__global__ __launch_bounds__(256) void k_gemm(const float* __restrict__ feat,
                                              const short* __restrict__ wfrag,
                                              unsigned short* __restrict__ hb,
                                              float* __restrict__ el,
                                              float* __restrict__ er, int N,
                                              const int* __restrict__ dst,
                                              int* __restrict__ bcount,
                                              int E, int NB) {
    __shared__ short wlds[32768];   // 64 KB: slots ks*8+nt (nt<8)
    __shared__ int bh[512];         // bucket histogram
    const int t    = threadIdx.x;
    const int lane = t & 63;
    const int wave = t >> 6;
    const int n0   = blockIdx.x * 64;
    const int g    = lane >> 4;     // k-quad
    const int c    = lane & 15;
    const bool do_hist = (blockIdx.x * BIN_EDGES) < E;

    if (do_hist) {
        for (int i = t; i < 512; i += 256) bh[i] = 0;
    }

    // ---- stage W ntiles 0..7: linear 16 B chunks, skip every 9th slot
#pragma unroll
    for (int i = 0; i < 16; i++) {
        int p  = t + i * 256;                   // chunk 0..4095
        int sl = p >> 6, li = p & 63;           // lds slot, lane-in-slot
        int gs = (sl >> 3) * 9 + (sl & 7);      // global slot
        *(short8v*)&wlds[(size_t)p * 8] =
            *(const short8v*)&wfrag[((size_t)gs * 64 + li) * 8];
    }

    // ---- issue the wave's entire A slice (before the barrier: independent)
    const int row = n0 + wave * 16 + c;
    const int rc  = row < N ? row : N - 1;
    const float* ap = feat + (size_t)rc * 256 + g * 8;
    float4 a4[16];
#pragma unroll
    for (int ks = 0; ks < 8; ks++) {
        a4[2 * ks]     = *(const float4*)(ap + ks * 32);
        a4[2 * ks + 1] = *(const float4*)(ap + ks * 32 + 4);
    }

    __syncthreads();

    f32x4 acc[9];
#pragma unroll
    for (int nt = 0; nt < 9; nt++) acc[nt] = (f32x4){0.f, 0.f, 0.f, 0.f};

#pragma unroll
    for (int ks = 0; ks < 8; ks++) {
        float4 v0 = a4[2 * ks], v1 = a4[2 * ks + 1];
        short s8[8];
        s8[0] = (short)f2bf(v0.x); s8[1] = (short)f2bf(v0.y);
        s8[2] = (short)f2bf(v0.z); s8[3] = (short)f2bf(v0.w);
        s8[4] = (short)f2bf(v1.x); s8[5] = (short)f2bf(v1.y);
        s8[6] = (short)f2bf(v1.z); s8[7] = (short)f2bf(v1.w);
        short8v afrag = *(short8v*)s8;
        short8v b8 = *(const short8v*)&wfrag[(((size_t)ks * 9 + 8) * 64 + lane) * 8];
#pragma unroll
        for (int nt = 0; nt < 8; nt++) {
            short8v b = *(short8v*)&wlds[(((size_t)ks * 8 + nt) * 64 + lane) * 8];
            acc[nt] = __builtin_amdgcn_mfma_f32_16x16x32_bf16(afrag, b, acc[nt], 0, 0, 0);
        }
        acc[8] = __builtin_amdgcn_mfma_f32_16x16x32_bf16(afrag, b8, acc[8], 0, 0, 0);
    }

    // ---- epilogue: C/D layout col = nt*16 + c, row = wave*16 + g*4 + r
#pragma unroll
    for (int r = 0; r < 4; r++) {
        int m = n0 + wave * 16 + g * 4 + r;
        if (m < N) {
#pragma unroll
            for (int nt = 0; nt < 8; nt++)
                hb[(size_t)m * 128 + nt * 16 + c] = f2bf(acc[nt][r]);
            float av = acc[8][r];
            if (c < 4)      el[(size_t)m * 4 + c]       = av;
            else if (c < 8) er[(size_t)m * 4 + (c - 4)] = av;
        }
    }

    // ---- fused bucket histogram (slice of 4096 edges)
    if (do_hist) {
        int base = blockIdx.x * BIN_EDGES + t;
#pragma unroll
        for (int k = 0; k < BIN_EPT; k++) {
            int idx = base + k * 256;
            if (idx < E) atomicAdd(&bh[dst[idx] >> NPB_SHIFT], 1);
        }
        __syncthreads();
        for (int i = t; i < NB; i += 256) {
            int h = bh[i];
            if (h) atomicAdd(&bcount[i], h);
        }
    }
}

// single-WG scan of bucket counts -> bucket bases + cursors; also start[N]=E
__global__ __launch_bounds__(512) void k_bscan(const int* __restrict__ bcount,
                                               int* __restrict__ bbase,
                                               int* __restrict__ bcur,
                                               int* __restrict__ startA,
                                               int NB, int N) {
    __shared__ int s[512];
    int t = threadIdx.x;
    int h = (t < NB) ? bcount[t] : 0;
    s[t] = h;
    __syncthreads();
    for (int off = 1; off < 512; off <<= 1) {
        int v = (t >= off) ? s[t - off] : 0;
        __syncthreads();
        s[t] += v;
        __syncthreads();
    }
    int excl = s[t] - h;
    if (t <= NB) bbase[t] = excl;     // bbase[NB] = E
    if (t < NB)  bcur[t]  = excl;
    if (t == 0)  startA[N] = s[511];  // total = E
}

// scatter edges into bucket-contiguous order, packed src|ldst<<24 (4 B/edge).
// LDS-reorder: locally sort the WG's edges by bucket so the global writes are
// linear (consecutive lanes -> consecutive addresses within each bucket run,
// HW-coalesced) instead of 4096 scattered 4-B transactions.
__global__ __launch_bounds__(256) void k_binscatter(const int* __restrict__ src,
                                                    const int* __restrict__ dst,
                                                    int* __restrict__ bcur,
                                                    unsigned int* __restrict__ binned,
                                                    int E, int NB) {
    __shared__ int hist[512];
    __shared__ int scn[512];
    __shared__ int lcur[512];
    __shared__ int gdelta[512];
    __shared__ int ebuf[BIN_EDGES];   // 16 KB: src per local slot
    __shared__ int dbuf[BIN_EDGES];   // 16 KB: dst per local slot
    int t = threadIdx.x;
    for (int i = t; i < 512; i += 256) hist[i] = 0;
    __syncthreads();
    int wbase = blockIdx.x * BIN_EDGES;
    int base  = wbase + t;
    int ne    = E - wbase; if (ne > BIN_EDGES) ne = BIN_EDGES;
    int sv[BIN_EPT], dv[BIN_EPT];
#pragma unroll
    for (int k = 0; k < BIN_EPT; k++) {
        int idx = base + k * 256;
        if (idx < E) {
            sv[k] = src[idx];
            dv[k] = dst[idx];
            atomicAdd(&hist[dv[k] >> NPB_SHIFT], 1);
        } else {
            dv[k] = -1;
        }
    }
    __syncthreads();
    // inclusive scan of 512 counts with 256 threads (Hillis-Steele)
    scn[t] = hist[t]; scn[t + 256] = hist[t + 256];
    __syncthreads();
    for (int off = 1; off < 512; off <<= 1) {
        int a0 = (t >= off) ? scn[t - off] : 0;
        int a1 = (t + 256 >= off) ? scn[t + 256 - off] : 0;
        __syncthreads();
        scn[t] += a0; scn[t + 256] += a1;
        __syncthreads();
    }
    // claim global ranges; set local cursors
    for (int i = t; i < NB; i += 256) {
        int h  = hist[i];
        int lb = scn[i] - h;
        int g  = h ? atomicAdd(&bcur[i], h) : 0;
        gdelta[i] = g - lb;
        lcur[i]   = lb;
    }
    __syncthreads();
    // local scatter into bucket-sorted LDS order
#pragma unroll
    for (int k = 0; k < BIN_EPT; k++) {
        if (dv[k] >= 0) {
            int bkt  = dv[k] >> NPB_SHIFT;
            int slot = atomicAdd(&lcur[bkt], 1);
            ebuf[slot] = sv[k];
            dbuf[slot] = dv[k];
        }
    }
    __syncthreads();
    // linear write-out: address = slot + gdelta[bucket]  (coalesced runs)
    for (int j = t; j < ne; j += 256) {
        int d = dbuf[j];
        binned[j + gdelta[d >> NPB_SHIFT]] =
            (unsigned int)ebuf[j] | ((unsigned int)(d & 255) << 24);
    }
}

// one WG per bucket: degree hist -> start, then LDS-stage the node-sorted
// edges and write the bucket's CSR segment with one linear coalesced pass.
__global__ __launch_bounds__(256) void k_csr(const unsigned int* __restrict__ binned,
                                             const int* __restrict__ bbase,
                                             int* __restrict__ startA,
                                             int* __restrict__ src_csr, int N) {
    __shared__ int hist[256];
    __shared__ int scn[256];
    __shared__ int cur[256];
    __shared__ int sbuf[3072];   // 12 KB staging (max bucket ~2.8K edges)
    int b = blockIdx.x;
    int t = threadIdx.x;
    int base = bbase[b];
    int cnt  = bbase[b + 1] - base;
    int node0 = b << NPB_SHIFT;
    hist[t] = 0;
    __syncthreads();
    for (int i = t; i < cnt; i += 256) {
        unsigned int e = binned[base + i];
        atomicAdd(&hist[e >> 24], 1);
    }
    __syncthreads();
    int h = hist[t];
    scn[t] = h;
    __syncthreads();
    for (int off = 1; off < 256; off <<= 1) {
        int v = (t >= off) ? scn[t - off] : 0;
        __syncthreads();
        scn[t] += v;
        __syncthreads();
    }
    int excl  = scn[t] - h;
    int gnode = node0 + t;
    if (gnode < N) startA[gnode] = base + excl;
    cur[t] = excl;
    __syncthreads();
    if (cnt <= 3072) {
        for (int i = t; i < cnt; i += 256) {
            unsigned int e = binned[base + i];
            int p = atomicAdd(&cur[e >> 24], 1);
            sbuf[p] = (int)(e & 0xFFFFFFu);
        }
        __syncthreads();
        for (int i = t; i < cnt; i += 256)
            src_csr[base + i] = sbuf[i];
    } else {
        // fallback: direct scatter (degenerate distributions only)
        for (int i = t; i < cnt; i += 256) {
            unsigned int e = binned[base + i];
            int p = atomicAdd(&cur[e >> 24], 1);
            src_csr[base + p] = (int)(e & 0xFFFFFFu);
        }
    }
}

// ---------------- gather-side aggregation: one wave per dst node -------------
// unroll-8 with batched index/gather issue (8 outstanding 256-B gathers per
// wave) to hide LLC-hit latency; degree from start[w+1]-start[w].
__global__ __launch_bounds__(256) void k_agg(
        const unsigned int* __restrict__ hbu,
        const float* __restrict__ el, const float* __restrict__ er,
        const int* __restrict__ src_csr, const int* __restrict__ start,
        const float* __restrict__ bias, float* __restrict__ out, int N) {
    int wid  = blockIdx.x * 4 + (threadIdx.x >> 6);
    int lane = threadIdx.x & 63;
    if (wid >= N) return;
    int beg = __builtin_amdgcn_readfirstlane(start[wid]);
    int end = __builtin_amdgcn_readfirstlane(start[wid + 1]);
    int dg  = end - beg;
    int head = lane >> 4;   // elements (2*lane, 2*lane+1) share one head

    float er_own = er[(size_t)wid * 4 + head];   // wave-uniform per 16-lane group
    unsigned int uh = hbu[(size_t)wid * 64 + lane];  // own row, issued early
    float2 bv = ((const float2*)bias)[lane];

    float S1x = 0.f, S1y = 0.f, S2x = 0.f, S2y = 0.f, dd = 0.f;
    int i = 0;
    for (; i + 8 <= dg; i += 8) {
        int b = beg + i;
        int s[8];
#pragma unroll
        for (int k = 0; k < 8; k++) s[k] = src_csr[b + k];
        unsigned int u[8];
#pragma unroll
        for (int k = 0; k < 8; k++) u[k] = hbu[(size_t)s[k] * 64 + lane];
        float ev[8];
#pragma unroll
        for (int k = 0; k < 8; k++) ev[k] = el[(size_t)s[k] * 4 + head];
#pragma unroll
        for (int k = 0; k < 8; k++) {
            float tt = ev[k] + er_own;
            tt = fmaxf(tt, NEG_SLOPE * tt);
            float w = __expf(tt);
            float x = uas(u[k] << 16), y = uas(u[k] & 0xFFFF0000u);
            S1x += x; S1y += y;
            S2x += w * x; S2y += w * y;
            dd  += w;
        }
    }
    for (; i + 4 <= dg; i += 4) {
        int b = beg + i;
        int s[4];
#pragma unroll
        for (int k = 0; k < 4; k++) s[k] = src_csr[b + k];
        unsigned int u[4];
#pragma unroll
        for (int k = 0; k < 4; k++) u[k] = hbu[(size_t)s[k] * 64 + lane];
        float ev[4];
#pragma unroll
        for (int k = 0; k < 4; k++) ev[k] = el[(size_t)s[k] * 4 + head];
#pragma unroll
        for (int k = 0; k < 4; k++) {
            float tt = ev[k] + er_own;
            tt = fmaxf(tt, NEG_SLOPE * tt);
            float w = __expf(tt);
            float x = uas(u[k] << 16), y = uas(u[k] & 0xFFFF0000u);
            S1x += x; S1y += y;
            S2x += w * x; S2y += w * y;
            dd  += w;
        }
    }
    for (; i < dg; i++) {
        int s0 = src_csr[beg + i];
        unsigned int u0 = hbu[(size_t)s0 * 64 + lane];
        float tt = el[(size_t)s0 * 4 + head] + er_own;
        tt = fmaxf(tt, NEG_SLOPE * tt);
        float w0 = __expf(tt);
        float x0 = uas(u0 << 16), y0 = uas(u0 & 0xFFFF0000u);
        S1x += x0; S1y += y0;
        S2x += w0 * x0; S2y += w0 * y0;
        dd  += w0;
    }

    float hvx = uas(uh << 16), hvy = uas(uh & 0xFFFF0000u);
    float inv = dd > 0.f ? 1.f / dd : 0.f;
    float ox = bv.x + hvx * S1x + S2x * inv;
    float oy = bv.y + hvy * S1y + S2y * inv;
    float2 o = {ox, oy};
    ((float2*)(out + (size_t)wid * 128))[lane] = o;
}

extern "C" void kernel_launch(void* const* d_in, const int* in_sizes, int n_in,
                              void* d_out, int out_size, void* d_ws, size_t ws_size,
                              hipStream_t stream) {
    const float* feat = (const float*)d_in[0];
    const float* W_fc = (const float*)d_in[1];
    const float* al   = (const float*)d_in[2];
    const float* ar   = (const float*)d_in[3];
    const float* bias = (const float*)d_in[4];
    const int*   src  = (const int*)d_in[5];
    const int*   dst  = (const int*)d_in[6];
    const int N = in_sizes[0] / 256;
    const int E = in_sizes[5];
    const int NB = (N + 255) >> NPB_SHIFT;   // <= 512 for N <= 131072

    char* ws = (char*)d_ws;
    size_t off = 0;
    unsigned int* hbu = (unsigned int*)(ws + off); off += (size_t)N * 64 * 4; // 25.6 MB
    float* el         = (float*)(ws + off); off += (size_t)N * 4 * 4;         // 1.6 MB
    float* er         = (float*)(ws + off); off += (size_t)N * 4 * 4;         // 1.6 MB
    int* startA       = (int*)(ws + off);   off += (size_t)(N + 1) * 4;
    int* src_csr      = (int*)(ws + off);   off += (size_t)E * 4;             // 4 MB
    unsigned int* binned = (unsigned int*)(ws + off); off += (size_t)E * 4;   // 4 MB
    short* wfrag      = (short*)(ws + off); off += (size_t)72 * 64 * 8 * 2;   // 72 KB
    int* bcount       = (int*)(ws + off);   off += 2048;
    int* bbase        = (int*)(ws + off);   off += 2064;                      // NB+1
    int* bcur         = (int*)(ws + off);   off += 2048;

    float* out = (float*)d_out;

    k_prep<<<18, 256, 0, stream>>>(W_fc, al, ar, wfrag, bcount, NB);
    k_gemm<<<(N + 63) / 64, 256, 0, stream>>>(feat, wfrag, (unsigned short*)hbu,
                                              el, er, N, dst, bcount, E, NB);
    int binWG = (E + BIN_EDGES - 1) / BIN_EDGES;
    k_bscan<<<1, 512, 0, stream>>>(bcount, bbase, bcur, startA, NB, N);
    k_binscatter<<<binWG, 256, 0, stream>>>(src, dst, bcur, binned, E, NB);
    k_csr<<<NB, 256, 0, stream>>>(binned, bbase, startA, src_csr, N);
    k_agg<<<(N + 3) / 4, 256, 0, stream>>>(hbu, el, er, src_csr, startA,
                                           bias, out, N);
}